// Round 2
// baseline (7797.990 us; speedup 1.0000x reference)
//
#include <hip/hip_runtime.h>
#include <hip/hip_bf16.h>
#include <cstddef>

// ---- problem constants ----
#define NN     50000
#define NE     800000
#define IND    128
#define EMBD   64
#define IN1    192     // IND + EMBD
#define HDIM   256
#define RR     12
#define BB     8
#define NHEADS 4
#define NGENE  20000
#define NPATH  2000
#define RC     2       // relations per scatter chunk (6 chunks)

// ---------- build x0 = [x | emb] in fp32 ----------
__global__ void k_build_x0(const float* __restrict__ x, float* __restrict__ x0) {
  int t = blockIdx.x * 256 + threadIdx.x;
  if (t >= NN * IN1) return;
  int n = t / IN1, i = t - n * IN1;
  x0[t] = (i < IND) ? x[(size_t)n * IND + i] : 0.0f;
}

__global__ void k_add_emb(const int* __restrict__ idx, const float* __restrict__ emb,
                          float* __restrict__ x0, int count) {
  int t = blockIdx.x * 256 + threadIdx.x;
  if (t >= count * EMBD) return;
  int g = t / EMBD, j = t - g * EMBD;
  int n = idx[g];
  x0[(size_t)n * IN1 + IND + j] += emb[t];
}

// ---------- per-(dst,rel) edge counts ----------
__global__ void k_count(const int* __restrict__ ei, const int* __restrict__ et,
                        float* __restrict__ cnt) {
  int e = blockIdx.x * 256 + threadIdx.x;
  if (e >= NE) return;
  int dst = ei[NE + e];
  int r = et[e];
  atomicAdd(&cnt[dst * RR + r], 1.0f);
}

// ---------- W[r] = sum_b comp[r,b] * basis[b] (fp32) ----------
__global__ void k_wcat(const float* __restrict__ comp, const float* __restrict__ basis,
                       float* __restrict__ W, int in_dim) {
  int t = blockIdx.x * 256 + threadIdx.x;
  int total = RR * in_dim * HDIM;
  if (t >= total) return;
  int o = t % HDIM;
  int i = (t / HDIM) % in_dim;
  int r = t / (HDIM * in_dim);
  float acc = 0.f;
#pragma unroll
  for (int b = 0; b < BB; b++)
    acc += comp[r * BB + b] * basis[((size_t)b * in_dim + i) * HDIM + o];
  W[t] = acc;
}

// ---------- h[n,o] = bias[o] ----------
__global__ void k_init_bias(const float* __restrict__ bias, float* __restrict__ h) {
  int t = blockIdx.x * 256 + threadIdx.x;
  if (t >= NN * HDIM) return;
  h[t] = bias[t & (HDIM - 1)];
}

// ---------- scatter: aggC[dst, et-r0, :] += w * xin[src, :]  (fp32 atomics) ----------
__global__ void k_scatter(const int* __restrict__ ei, const int* __restrict__ et,
                          const float* __restrict__ cnt, const float* __restrict__ xin,
                          float* __restrict__ aggC, int in_dim, int r0) {
  int t = blockIdx.x * 256 + threadIdx.x;
  int g4 = in_dim >> 2;
  int e = t / g4;
  if (e >= NE) return;
  int r = et[e];
  int rl = r - r0;
  if (rl < 0 || rl >= RC) return;
  int i = (t - e * g4) * 4;
  int src = ei[e];
  int dst = ei[NE + e];
  float w = 1.0f / fmaxf(cnt[dst * RR + r], 1.0f);
  const float* xs = xin + (size_t)src * in_dim + i;
  float* ag = aggC + ((size_t)dst * RC + rl) * in_dim + i;
  atomicAdd(ag + 0, w * xs[0]);
  atomicAdd(ag + 1, w * xs[1]);
  atomicAdd(ag + 2, w * xs[2]);
  atomicAdd(ag + 3, w * xs[3]);
}

// ---------- fp32 SIMT GEMM: C[NN,256] += A[NN,K] @ B[K,256] ----------
__global__ __launch_bounds__(256) void k_gemm_acc(const float* __restrict__ A,
                                                  const float* __restrict__ B,
                                                  float* __restrict__ C, int K) {
  __shared__ float As[16][129];
  __shared__ float Bs[16][65];
  int bm = blockIdx.x * 128;
  int bn = blockIdx.y * 64;
  int tid = threadIdx.x;
  int tx = tid & 15, ty = tid >> 4;
  float acc[8][4];
#pragma unroll
  for (int i = 0; i < 8; i++)
#pragma unroll
    for (int j = 0; j < 4; j++) acc[i][j] = 0.f;

  for (int k0 = 0; k0 < K; k0 += 16) {
    int arow = tid >> 1;
    int ak = (tid & 1) * 8;
    int grow = bm + arow;
    float4 v0 = {0, 0, 0, 0}, v1 = {0, 0, 0, 0};
    if (grow < NN) {
      const float* ap = A + (size_t)grow * K + k0 + ak;
      v0 = *(const float4*)ap;
      v1 = *(const float4*)(ap + 4);
    }
    As[ak + 0][arow] = v0.x; As[ak + 1][arow] = v0.y;
    As[ak + 2][arow] = v0.z; As[ak + 3][arow] = v0.w;
    As[ak + 4][arow] = v1.x; As[ak + 5][arow] = v1.y;
    As[ak + 6][arow] = v1.z; As[ak + 7][arow] = v1.w;
    int bk = tid >> 4;
    int bcol = (tid & 15) * 4;
    float4 bv = *(const float4*)(B + (size_t)(k0 + bk) * HDIM + bn + bcol);
    Bs[bk][bcol + 0] = bv.x; Bs[bk][bcol + 1] = bv.y;
    Bs[bk][bcol + 2] = bv.z; Bs[bk][bcol + 3] = bv.w;
    __syncthreads();
#pragma unroll
    for (int k = 0; k < 16; k++) {
      float a[8], b[4];
#pragma unroll
      for (int i = 0; i < 8; i++) a[i] = As[k][ty * 8 + i];
#pragma unroll
      for (int j = 0; j < 4; j++) b[j] = Bs[k][tx * 4 + j];
#pragma unroll
      for (int i = 0; i < 8; i++)
#pragma unroll
        for (int j = 0; j < 4; j++) acc[i][j] += a[i] * b[j];
    }
    __syncthreads();
  }
#pragma unroll
  for (int i = 0; i < 8; i++) {
    int row = bm + ty * 8 + i;
    if (row < NN) {
      float* cp = C + (size_t)row * HDIM + bn + tx * 4;
#pragma unroll
      for (int j = 0; j < 4; j++) cp[j] += acc[i][j];
    }
  }
}

// ---------- head-softmax attention, in place. one wave per node ----------
__global__ void k_attn(float* __restrict__ h, const float* __restrict__ att) {
  int gtid = blockIdx.x * 256 + threadIdx.x;
  int node = gtid >> 6;
  int lane = gtid & 63;
  if (node >= NN) return;
  float* hp = h + (size_t)node * HDIM;
  float v[NHEADS], s[NHEADS];
#pragma unroll
  for (int hd = 0; hd < NHEADS; hd++) {
    v[hd] = hp[hd * 64 + lane];
    s[hd] = v[hd] * att[hd * 64 + lane];
  }
#pragma unroll
  for (int off = 32; off > 0; off >>= 1) {
#pragma unroll
    for (int hd = 0; hd < NHEADS; hd++) s[hd] += __shfl_xor(s[hd], off, 64);
  }
  float mx = fmaxf(fmaxf(s[0], s[1]), fmaxf(s[2], s[3]));
  float ex[NHEADS], sum = 0.f;
#pragma unroll
  for (int hd = 0; hd < NHEADS; hd++) { ex[hd] = __expf(s[hd] - mx); sum += ex[hd]; }
  float inv = 1.0f / sum;
#pragma unroll
  for (int hd = 0; hd < NHEADS; hd++) hp[hd * 64 + lane] = v[hd] * (ex[hd] * inv);
}

// ---------- prediction head: out[n,j] = h[n,:] @ pred_w[:,j] + pred_b[j] ----------
__global__ void k_pred(const float* __restrict__ h, const float* __restrict__ w,
                       const float* __restrict__ b, float* __restrict__ out) {
  int t = blockIdx.x * 256 + threadIdx.x;
  if (t >= NN * 12) return;
  int n = t / 12, j = t - n * 12;
  float acc = b[j];
  const float* hp = h + (size_t)n * HDIM;
#pragma unroll 4
  for (int k = 0; k < HDIM; k++) acc += hp[k] * w[k * 12 + j];
  out[t] = acc;
}

extern "C" void kernel_launch(void* const* d_in, const int* in_sizes, int n_in,
                              void* d_out, int out_size, void* d_ws, size_t ws_size,
                              hipStream_t stream) {
  const float* x         = (const float*)d_in[0];
  const int*   edge_idx  = (const int*)d_in[1];
  const int*   edge_type = (const int*)d_in[2];
  const int*   gene_idx  = (const int*)d_in[3];
  const int*   path_idx  = (const int*)d_in[4];
  const float* gene_emb  = (const float*)d_in[5];
  const float* path_emb  = (const float*)d_in[6];
  const float* comp1     = (const float*)d_in[7];
  const float* basis1    = (const float*)d_in[8];
  const float* root1     = (const float*)d_in[9];
  const float* bias1     = (const float*)d_in[10];
  const float* att1      = (const float*)d_in[11];
  const float* comp2     = (const float*)d_in[12];
  const float* basis2    = (const float*)d_in[13];
  const float* root2     = (const float*)d_in[14];
  const float* bias2     = (const float*)d_in[15];
  const float* att2      = (const float*)d_in[16];
  const float* pred_w    = (const float*)d_in[17];
  const float* pred_b    = (const float*)d_in[18];
  float* out = (float*)d_out;

  // workspace layout (bytes), all 16B aligned; peak ~252 MB
  char* ws = (char*)d_ws;
  float* x0   = (float*)(ws);                       // 50000*192*4  = 38,400,000
  float* h1   = (float*)(ws + 38400000);            // 51,200,000
  float* h2   = (float*)(ws + 89600000);            // 51,200,000
  float* cnt  = (float*)(ws + 140800000);           // 2,400,000
  float* W1   = (float*)(ws + 143200000);           // 12*192*256*4 = 2,359,296
  float* W2   = (float*)(ws + 145559296);           // 12*256*256*4 = 3,145,728
  float* aggC = (float*)(ws + 149163776);           // 50000*RC*256*4 = 102,400,000

  dim3 blk(256);

  // ---- stage 0: x0, counts, weight prep ----
  k_build_x0<<<dim3((NN * IN1) / 256), blk, 0, stream>>>(x, x0);
  k_add_emb<<<dim3((NGENE * EMBD) / 256), blk, 0, stream>>>(gene_idx, gene_emb, x0, NGENE);
  k_add_emb<<<dim3((NPATH * EMBD) / 256), blk, 0, stream>>>(path_idx, path_emb, x0, NPATH);
  hipMemsetAsync(cnt, 0, NN * RR * 4, stream);
  k_count<<<dim3(NE / 256), blk, 0, stream>>>(edge_idx, edge_type, cnt);
  k_wcat<<<dim3((RR * IN1 * HDIM) / 256), blk, 0, stream>>>(comp1, basis1, W1, IN1);
  k_wcat<<<dim3((RR * HDIM * HDIM) / 256), blk, 0, stream>>>(comp2, basis2, W2, HDIM);

  dim3 ggrid(391, 4);  // ceil(50000/128) x (256/64)

  // ---- conv1 ----
  k_init_bias<<<dim3((NN * HDIM) / 256), blk, 0, stream>>>(bias1, h1);
  k_gemm_acc<<<ggrid, blk, 0, stream>>>(x0, root1, h1, IN1);
  for (int c = 0; c < RR / RC; c++) {
    hipMemsetAsync(aggC, 0, (size_t)NN * RC * IN1 * 4, stream);
    k_scatter<<<dim3((NE * (IN1 / 4)) / 256), blk, 0, stream>>>(
        edge_idx, edge_type, cnt, x0, aggC, IN1, c * RC);
    k_gemm_acc<<<ggrid, blk, 0, stream>>>(aggC, W1 + (size_t)c * RC * IN1 * HDIM, h1, RC * IN1);
  }
  k_attn<<<dim3((NN * 64 + 255) / 256), blk, 0, stream>>>(h1, att1);

  // ---- conv2 ----
  k_init_bias<<<dim3((NN * HDIM) / 256), blk, 0, stream>>>(bias2, h2);
  k_gemm_acc<<<ggrid, blk, 0, stream>>>(h1, root2, h2, HDIM);
  for (int c = 0; c < RR / RC; c++) {
    hipMemsetAsync(aggC, 0, (size_t)NN * RC * HDIM * 4, stream);
    k_scatter<<<dim3((NE * (HDIM / 4)) / 256), blk, 0, stream>>>(
        edge_idx, edge_type, cnt, h1, aggC, HDIM, c * RC);
    k_gemm_acc<<<ggrid, blk, 0, stream>>>(aggC, W2 + (size_t)c * RC * HDIM * HDIM, h2, RC * HDIM);
  }
  k_attn<<<dim3((NN * 64 + 255) / 256), blk, 0, stream>>>(h2, att2);

  // ---- prediction head ----
  k_pred<<<dim3((NN * 12 + 255) / 256), blk, 0, stream>>>(h2, pred_w, pred_b, out);
}

// Round 3
// 3272.902 us; speedup vs baseline: 2.3826x; 2.3826x over previous
//
#include <hip/hip_runtime.h>
#include <hip/hip_bf16.h>
#include <cstddef>

// ---- problem constants ----
#define NN     50000
#define NE     800000
#define IND    128
#define EMBD   64
#define IN1    192     // IND + EMBD
#define HDIM   256
#define RR     12
#define BB     8
#define NHEADS 4
#define NGENE  20000
#define NPATH  2000
#define RC     2       // relations per chunk (6 chunks)
#define NRK    (RR * NN)              // 600000 segment keys
#define SCB    1024                   // elements per scan block
#define NSB    ((NRK + SCB - 1) / SCB) // 586

// ---------- build x0 = [x | emb] in fp32 ----------
__global__ void k_build_x0(const float* __restrict__ x, float* __restrict__ x0) {
  int t = blockIdx.x * 256 + threadIdx.x;
  if (t >= NN * IN1) return;
  int n = t / IN1, i = t - n * IN1;
  x0[t] = (i < IND) ? x[(size_t)n * IND + i] : 0.0f;
}

__global__ void k_add_emb(const int* __restrict__ idx, const float* __restrict__ emb,
                          float* __restrict__ x0, int count) {
  int t = blockIdx.x * 256 + threadIdx.x;
  if (t >= count * EMBD) return;
  int g = t / EMBD, j = t - g * EMBD;
  int n = idx[g];
  x0[(size_t)n * IN1 + IND + j] += emb[t];
}

// ---------- per-(rel,dst) edge counts (int) ----------
__global__ void k_count(const int* __restrict__ ei, const int* __restrict__ et,
                        int* __restrict__ cnt) {
  int e = blockIdx.x * 256 + threadIdx.x;
  if (e >= NE) return;
  atomicAdd(&cnt[et[e] * NN + ei[NE + e]], 1);
}

// ---------- 3-kernel exclusive scan over cnt[NRK] -> off[NRK] ----------
__global__ __launch_bounds__(256) void k_scan1(const int* __restrict__ cnt,
                                               int* __restrict__ bsum) {
  __shared__ int lds[256];
  int t = threadIdx.x;
  int base = blockIdx.x * SCB + t * 4;
  int s = 0;
#pragma unroll
  for (int j = 0; j < 4; j++) { int idx = base + j; if (idx < NRK) s += cnt[idx]; }
  lds[t] = s; __syncthreads();
  for (int d = 128; d > 0; d >>= 1) { if (t < d) lds[t] += lds[t + d]; __syncthreads(); }
  if (t == 0) bsum[blockIdx.x] = lds[0];
}

__global__ __launch_bounds__(1024) void k_scan2(const int* __restrict__ bsum,
                                                int* __restrict__ bscan) {
  __shared__ int lds[1024];
  int t = threadIdx.x;
  int v = (t < NSB) ? bsum[t] : 0;
  lds[t] = v; __syncthreads();
  for (int d = 1; d < 1024; d <<= 1) {
    int add = (t >= d) ? lds[t - d] : 0; __syncthreads();
    lds[t] += add; __syncthreads();
  }
  if (t < NSB) bscan[t] = lds[t] - v;  // exclusive
}

__global__ __launch_bounds__(256) void k_scan3(const int* __restrict__ cnt,
                                               const int* __restrict__ bscan,
                                               int* __restrict__ off) {
  __shared__ int lds[256];
  int t = threadIdx.x;
  int base = blockIdx.x * SCB + t * 4;
  int v[4]; int s = 0;
#pragma unroll
  for (int j = 0; j < 4; j++) { int idx = base + j; v[j] = (idx < NRK) ? cnt[idx] : 0; s += v[j]; }
  lds[t] = s; __syncthreads();
  for (int d = 1; d < 256; d <<= 1) {
    int add = (t >= d) ? lds[t - d] : 0; __syncthreads();
    lds[t] += add; __syncthreads();
  }
  int ex = lds[t] - s + bscan[blockIdx.x];
#pragma unroll
  for (int j = 0; j < 4; j++) {
    int idx = base + j;
    if (idx < NRK) { off[idx] = ex; ex += v[j]; }
  }
}

// ---------- fill edge permutation ----------
__global__ void k_fill(const int* __restrict__ ei, const int* __restrict__ et,
                       const int* __restrict__ off, int* __restrict__ fill,
                       int* __restrict__ perm) {
  int e = blockIdx.x * 256 + threadIdx.x;
  if (e >= NE) return;
  int key = et[e] * NN + ei[NE + e];
  int pos = off[key] + atomicAdd(&fill[key], 1);
  perm[pos] = e;
}

// ---------- CSR gather aggregation: one wave per (dst, rl) segment ----------
__global__ __launch_bounds__(256) void k_agg(const int* __restrict__ ei,
                                             const int* __restrict__ perm,
                                             const int* __restrict__ off,
                                             const int* __restrict__ cnt,
                                             const float* __restrict__ xin,
                                             float* __restrict__ aggC,
                                             int in_dim, int r0) {
  int wave = (blockIdx.x * 256 + threadIdx.x) >> 6;
  int lane = threadIdx.x & 63;
  int dst = wave >> 1;   // RC = 2
  int rl  = wave & 1;
  if (dst >= NN) return;
  int key = (r0 + rl) * NN + dst;
  int beg = off[key];
  int n   = cnt[key];
  int g4 = in_dim >> 2;
  bool act = lane < g4;
  float ax = 0.f, ay = 0.f, az = 0.f, aw = 0.f;
  for (int p = 0; p < n; p++) {
    int e = perm[beg + p];
    int src = ei[e];
    if (act) {
      const float4 v = *(const float4*)(xin + (size_t)src * in_dim + lane * 4);
      ax += v.x; ay += v.y; az += v.z; aw += v.w;
    }
  }
  if (act) {
    float s = 1.0f / (float)max(n, 1);
    float4 r; r.x = ax * s; r.y = ay * s; r.z = az * s; r.w = aw * s;
    *(float4*)(aggC + ((size_t)dst * RC + rl) * in_dim + lane * 4) = r;
  }
}

// ---------- W[r] = sum_b comp[r,b] * basis[b] (fp32) ----------
__global__ void k_wcat(const float* __restrict__ comp, const float* __restrict__ basis,
                       float* __restrict__ W, int in_dim) {
  int t = blockIdx.x * 256 + threadIdx.x;
  int total = RR * in_dim * HDIM;
  if (t >= total) return;
  int o = t % HDIM;
  int i = (t / HDIM) % in_dim;
  int r = t / (HDIM * in_dim);
  float acc = 0.f;
#pragma unroll
  for (int b = 0; b < BB; b++)
    acc += comp[r * BB + b] * basis[((size_t)b * in_dim + i) * HDIM + o];
  W[t] = acc;
}

// ---------- h[n,o] = bias[o] ----------
__global__ void k_init_bias(const float* __restrict__ bias, float* __restrict__ h) {
  int t = blockIdx.x * 256 + threadIdx.x;
  if (t >= NN * HDIM) return;
  h[t] = bias[t & (HDIM - 1)];
}

// ---------- fp32 SIMT GEMM: C[NN,256] += A[NN,K] @ B[K,256] ----------
__global__ __launch_bounds__(256) void k_gemm_acc(const float* __restrict__ A,
                                                  const float* __restrict__ B,
                                                  float* __restrict__ C, int K) {
  __shared__ float As[16][129];
  __shared__ float Bs[16][65];
  int bm = blockIdx.x * 128;
  int bn = blockIdx.y * 64;
  int tid = threadIdx.x;
  int tx = tid & 15, ty = tid >> 4;
  float acc[8][4];
#pragma unroll
  for (int i = 0; i < 8; i++)
#pragma unroll
    for (int j = 0; j < 4; j++) acc[i][j] = 0.f;

  for (int k0 = 0; k0 < K; k0 += 16) {
    int arow = tid >> 1;
    int ak = (tid & 1) * 8;
    int grow = bm + arow;
    float4 v0 = {0, 0, 0, 0}, v1 = {0, 0, 0, 0};
    if (grow < NN) {
      const float* ap = A + (size_t)grow * K + k0 + ak;
      v0 = *(const float4*)ap;
      v1 = *(const float4*)(ap + 4);
    }
    As[ak + 0][arow] = v0.x; As[ak + 1][arow] = v0.y;
    As[ak + 2][arow] = v0.z; As[ak + 3][arow] = v0.w;
    As[ak + 4][arow] = v1.x; As[ak + 5][arow] = v1.y;
    As[ak + 6][arow] = v1.z; As[ak + 7][arow] = v1.w;
    int bk = tid >> 4;
    int bcol = (tid & 15) * 4;
    float4 bv = *(const float4*)(B + (size_t)(k0 + bk) * HDIM + bn + bcol);
    Bs[bk][bcol + 0] = bv.x; Bs[bk][bcol + 1] = bv.y;
    Bs[bk][bcol + 2] = bv.z; Bs[bk][bcol + 3] = bv.w;
    __syncthreads();
#pragma unroll
    for (int k = 0; k < 16; k++) {
      float a[8], b[4];
#pragma unroll
      for (int i = 0; i < 8; i++) a[i] = As[k][ty * 8 + i];
#pragma unroll
      for (int j = 0; j < 4; j++) b[j] = Bs[k][tx * 4 + j];
#pragma unroll
      for (int i = 0; i < 8; i++)
#pragma unroll
        for (int j = 0; j < 4; j++) acc[i][j] += a[i] * b[j];
    }
    __syncthreads();
  }
#pragma unroll
  for (int i = 0; i < 8; i++) {
    int row = bm + ty * 8 + i;
    if (row < NN) {
      float* cp = C + (size_t)row * HDIM + bn + tx * 4;
#pragma unroll
      for (int j = 0; j < 4; j++) cp[j] += acc[i][j];
    }
  }
}

// ---------- head-softmax attention, in place. one wave per node ----------
__global__ void k_attn(float* __restrict__ h, const float* __restrict__ att) {
  int gtid = blockIdx.x * 256 + threadIdx.x;
  int node = gtid >> 6;
  int lane = gtid & 63;
  if (node >= NN) return;
  float* hp = h + (size_t)node * HDIM;
  float v[NHEADS], s[NHEADS];
#pragma unroll
  for (int hd = 0; hd < NHEADS; hd++) {
    v[hd] = hp[hd * 64 + lane];
    s[hd] = v[hd] * att[hd * 64 + lane];
  }
#pragma unroll
  for (int off = 32; off > 0; off >>= 1) {
#pragma unroll
    for (int hd = 0; hd < NHEADS; hd++) s[hd] += __shfl_xor(s[hd], off, 64);
  }
  float mx = fmaxf(fmaxf(s[0], s[1]), fmaxf(s[2], s[3]));
  float ex[NHEADS], sum = 0.f;
#pragma unroll
  for (int hd = 0; hd < NHEADS; hd++) { ex[hd] = __expf(s[hd] - mx); sum += ex[hd]; }
  float inv = 1.0f / sum;
#pragma unroll
  for (int hd = 0; hd < NHEADS; hd++) hp[hd * 64 + lane] = v[hd] * (ex[hd] * inv);
}

// ---------- prediction head ----------
__global__ void k_pred(const float* __restrict__ h, const float* __restrict__ w,
                       const float* __restrict__ b, float* __restrict__ out) {
  int t = blockIdx.x * 256 + threadIdx.x;
  if (t >= NN * 12) return;
  int n = t / 12, j = t - n * 12;
  float acc = b[j];
  const float* hp = h + (size_t)n * HDIM;
#pragma unroll 4
  for (int k = 0; k < HDIM; k++) acc += hp[k] * w[k * 12 + j];
  out[t] = acc;
}

extern "C" void kernel_launch(void* const* d_in, const int* in_sizes, int n_in,
                              void* d_out, int out_size, void* d_ws, size_t ws_size,
                              hipStream_t stream) {
  const float* x         = (const float*)d_in[0];
  const int*   edge_idx  = (const int*)d_in[1];
  const int*   edge_type = (const int*)d_in[2];
  const int*   gene_idx  = (const int*)d_in[3];
  const int*   path_idx  = (const int*)d_in[4];
  const float* gene_emb  = (const float*)d_in[5];
  const float* path_emb  = (const float*)d_in[6];
  const float* comp1     = (const float*)d_in[7];
  const float* basis1    = (const float*)d_in[8];
  const float* root1     = (const float*)d_in[9];
  const float* bias1     = (const float*)d_in[10];
  const float* att1      = (const float*)d_in[11];
  const float* comp2     = (const float*)d_in[12];
  const float* basis2    = (const float*)d_in[13];
  const float* root2     = (const float*)d_in[14];
  const float* bias2     = (const float*)d_in[15];
  const float* att2      = (const float*)d_in[16];
  const float* pred_w    = (const float*)d_in[17];
  const float* pred_b    = (const float*)d_in[18];
  float* out = (float*)d_out;

  // workspace layout (bytes, 16B aligned); peak ~221 MB (< proven 252 MB)
  char* ws = (char*)d_ws;
  float* x0    = (float*)(ws);               // region A: x0 (conv1) 38.4 MB
  float* h2    = (float*)(ws);               // region A reused: h2 (conv2) 51.2 MB
  float* h1    = (float*)(ws + 51200000);    // 51.2 MB
  float* aggC  = (float*)(ws + 102400000);   // 102.4 MB
  float* W1    = (float*)(ws + 204800000);   // 2,359,296
  float* W2    = (float*)(ws + 207159296);   // 3,145,728
  int*   cnt   = (int*)  (ws + 210305024);   // 2,400,000
  int*   off   = (int*)  (ws + 212705024);   // 2,400,000
  int*   fill  = (int*)  (ws + 215105024);   // 2,400,000
  int*   perm  = (int*)  (ws + 217505024);   // 3,200,000
  int*   bsum  = (int*)  (ws + 220705024);   // 4 KB
  int*   bscan = (int*)  (ws + 220709120);   // 4 KB

  dim3 blk(256);

  // ---- stage 0: features + CSR build + weight prep ----
  k_build_x0<<<dim3((NN * IN1) / 256), blk, 0, stream>>>(x, x0);
  k_add_emb<<<dim3((NGENE * EMBD) / 256), blk, 0, stream>>>(gene_idx, gene_emb, x0, NGENE);
  k_add_emb<<<dim3((NPATH * EMBD) / 256), blk, 0, stream>>>(path_idx, path_emb, x0, NPATH);
  hipMemsetAsync(cnt, 0, NRK * 4, stream);
  hipMemsetAsync(fill, 0, NRK * 4, stream);
  k_count<<<dim3(NE / 256), blk, 0, stream>>>(edge_idx, edge_type, cnt);
  k_scan1<<<dim3(NSB), blk, 0, stream>>>(cnt, bsum);
  k_scan2<<<dim3(1), dim3(1024), 0, stream>>>(bsum, bscan);
  k_scan3<<<dim3(NSB), blk, 0, stream>>>(cnt, bscan, off);
  k_fill<<<dim3(NE / 256), blk, 0, stream>>>(edge_idx, edge_type, off, fill, perm);
  k_wcat<<<dim3((RR * IN1 * HDIM) / 256), blk, 0, stream>>>(comp1, basis1, W1, IN1);
  k_wcat<<<dim3((RR * HDIM * HDIM) / 256), blk, 0, stream>>>(comp2, basis2, W2, HDIM);

  dim3 ggrid(391, 4);           // ceil(50000/128) x (256/64)
  dim3 agrid(NN * RC / 4);      // one wave per (dst, rl); 4 waves/block

  // ---- conv1 ----
  k_init_bias<<<dim3((NN * HDIM) / 256), blk, 0, stream>>>(bias1, h1);
  k_gemm_acc<<<ggrid, blk, 0, stream>>>(x0, root1, h1, IN1);
  for (int c = 0; c < RR / RC; c++) {
    k_agg<<<agrid, blk, 0, stream>>>(edge_idx, perm, off, cnt, x0, aggC, IN1, c * RC);
    k_gemm_acc<<<ggrid, blk, 0, stream>>>(aggC, W1 + (size_t)c * RC * IN1 * HDIM, h1, RC * IN1);
  }
  k_attn<<<dim3((NN * 64 + 255) / 256), blk, 0, stream>>>(h1, att1);

  // ---- conv2 (h2 overlaps x0's storage; x0 is dead by now) ----
  k_init_bias<<<dim3((NN * HDIM) / 256), blk, 0, stream>>>(bias2, h2);
  k_gemm_acc<<<ggrid, blk, 0, stream>>>(h1, root2, h2, HDIM);
  for (int c = 0; c < RR / RC; c++) {
    k_agg<<<agrid, blk, 0, stream>>>(edge_idx, perm, off, cnt, h1, aggC, HDIM, c * RC);
    k_gemm_acc<<<ggrid, blk, 0, stream>>>(aggC, W2 + (size_t)c * RC * HDIM * HDIM, h2, RC * HDIM);
  }
  k_attn<<<dim3((NN * 64 + 255) / 256), blk, 0, stream>>>(h2, att2);

  // ---- prediction head ----
  k_pred<<<dim3((NN * 12 + 255) / 256), blk, 0, stream>>>(h2, pred_w, pred_b, out);
}

// Round 4
// 1629.964 us; speedup vs baseline: 4.7841x; 2.0080x over previous
//
#include <hip/hip_runtime.h>
#include <cstddef>

// ---- problem constants ----
#define NN     50000
#define NE     800000
#define IND    128
#define EMBD   64
#define IN1    192     // IND + EMBD
#define HDIM   256
#define RR     12
#define BB     8
#define NGENE  20000
#define NPATH  2000
#define RC     4       // relations per chunk (3 chunks)
#define NRK    (RR * NN)               // 600000 segment keys
#define SCB    1024
#define NSB    ((NRK + SCB - 1) / SCB) // 586

typedef __attribute__((ext_vector_type(8))) short short8;
typedef __attribute__((ext_vector_type(4))) float f32x4;

__device__ __forceinline__ float bu2f(unsigned short u) {
  unsigned int x = ((unsigned int)u) << 16;
  return __builtin_bit_cast(float, x);
}
__device__ __forceinline__ unsigned short f2bu(float f) {
  unsigned int x = __builtin_bit_cast(unsigned int, f);
  unsigned int r = (x + 0x7fffu + ((x >> 16) & 1u)) >> 16;
  return (unsigned short)r;
}

// ---------- build x0 = [x | 0] bf16 ----------
__global__ void k_build_x0(const float* __restrict__ x, unsigned short* __restrict__ x0) {
  int t = blockIdx.x * 256 + threadIdx.x;
  if (t >= NN * IN1) return;
  int n = t / IN1, i = t - n * IN1;
  x0[t] = (i < IND) ? f2bu(x[(size_t)n * IND + i]) : (unsigned short)0;
}

// pure write (gene/path rows disjoint, tail starts at 0)
__global__ void k_add_emb(const int* __restrict__ idx, const float* __restrict__ emb,
                          unsigned short* __restrict__ x0, int count) {
  int t = blockIdx.x * 256 + threadIdx.x;
  if (t >= count * EMBD) return;
  int g = t / EMBD, j = t - g * EMBD;
  x0[(size_t)idx[g] * IN1 + IND + j] = f2bu(emb[t]);
}

// ---------- per-(rel,dst) edge counts ----------
__global__ void k_count(const int* __restrict__ ei, const int* __restrict__ et,
                        int* __restrict__ cnt) {
  int e = blockIdx.x * 256 + threadIdx.x;
  if (e >= NE) return;
  atomicAdd(&cnt[et[e] * NN + ei[NE + e]], 1);
}

// ---------- 3-kernel exclusive scan ----------
__global__ __launch_bounds__(256) void k_scan1(const int* __restrict__ cnt,
                                               int* __restrict__ bsum) {
  __shared__ int lds[256];
  int t = threadIdx.x;
  int base = blockIdx.x * SCB + t * 4;
  int s = 0;
#pragma unroll
  for (int j = 0; j < 4; j++) { int idx = base + j; if (idx < NRK) s += cnt[idx]; }
  lds[t] = s; __syncthreads();
  for (int d = 128; d > 0; d >>= 1) { if (t < d) lds[t] += lds[t + d]; __syncthreads(); }
  if (t == 0) bsum[blockIdx.x] = lds[0];
}

__global__ __launch_bounds__(1024) void k_scan2(const int* __restrict__ bsum,
                                                int* __restrict__ bscan) {
  __shared__ int lds[1024];
  int t = threadIdx.x;
  int v = (t < NSB) ? bsum[t] : 0;
  lds[t] = v; __syncthreads();
  for (int d = 1; d < 1024; d <<= 1) {
    int add = (t >= d) ? lds[t - d] : 0; __syncthreads();
    lds[t] += add; __syncthreads();
  }
  if (t < NSB) bscan[t] = lds[t] - v;
}

__global__ __launch_bounds__(256) void k_scan3(const int* __restrict__ cnt,
                                               const int* __restrict__ bscan,
                                               int* __restrict__ off) {
  __shared__ int lds[256];
  int t = threadIdx.x;
  int base = blockIdx.x * SCB + t * 4;
  int v[4]; int s = 0;
#pragma unroll
  for (int j = 0; j < 4; j++) { int idx = base + j; v[j] = (idx < NRK) ? cnt[idx] : 0; s += v[j]; }
  lds[t] = s; __syncthreads();
  for (int d = 1; d < 256; d <<= 1) {
    int add = (t >= d) ? lds[t - d] : 0; __syncthreads();
    lds[t] += add; __syncthreads();
  }
  int ex = lds[t] - s + bscan[blockIdx.x];
#pragma unroll
  for (int j = 0; j < 4; j++) {
    int idx = base + j;
    if (idx < NRK) { off[idx] = ex; ex += v[j]; }
  }
}

__global__ void k_fill(const int* __restrict__ ei, const int* __restrict__ et,
                       const int* __restrict__ off, int* __restrict__ fill,
                       int* __restrict__ perm) {
  int e = blockIdx.x * 256 + threadIdx.x;
  if (e >= NE) return;
  int key = et[e] * NN + ei[NE + e];
  int pos = off[key] + atomicAdd(&fill[key], 1);
  perm[pos] = e;
}

// ---------- CSR gather aggregation: one wave per (dst, rl); bf16 in/out ----------
__global__ __launch_bounds__(256) void k_agg(const int* __restrict__ ei,
                                             const int* __restrict__ perm,
                                             const int* __restrict__ off,
                                             const int* __restrict__ cnt,
                                             const unsigned short* __restrict__ xin,
                                             unsigned short* __restrict__ aggC,
                                             int in_dim, int r0) {
  int wave = (blockIdx.x * 256 + threadIdx.x) >> 6;
  int lane = threadIdx.x & 63;
  int dst = wave >> 2;   // RC = 4
  int rl  = wave & 3;
  if (dst >= NN) return;
  int key = (r0 + rl) * NN + dst;
  int beg = off[key];
  int n   = cnt[key];
  bool act = lane * 4 < in_dim;
  float a0 = 0.f, a1 = 0.f, a2 = 0.f, a3 = 0.f;
  for (int p = 0; p < n; p++) {
    int src = ei[perm[beg + p]];
    if (act) {
      ushort4 v = *(const ushort4*)(xin + (size_t)src * in_dim + lane * 4);
      a0 += bu2f(v.x); a1 += bu2f(v.y); a2 += bu2f(v.z); a3 += bu2f(v.w);
    }
  }
  if (act) {
    float s = 1.0f / (float)max(n, 1);
    ushort4 o;
    o.x = f2bu(a0 * s); o.y = f2bu(a1 * s); o.z = f2bu(a2 * s); o.w = f2bu(a3 * s);
    *(ushort4*)(aggC + ((size_t)dst * RC + rl) * in_dim + lane * 4) = o;
  }
}

// ---------- Wt[c][o][rl][i] = bf16( sum_b comp[c*4+rl,b]*basis[b,i,o] ) ----------
__global__ void k_wcat(const float* __restrict__ comp, const float* __restrict__ basis,
                       unsigned short* __restrict__ Wt, int in_dim) {
  int t = blockIdx.x * 256 + threadIdx.x;
  int total = RR * HDIM * in_dim;
  if (t >= total) return;
  int i = t % in_dim;
  int rest = t / in_dim;     // (c*256+o)*4+rl
  int rl = rest & 3;
  int oc = rest >> 2;
  int o = oc & 255;
  int c = oc >> 8;
  int r = c * 4 + rl;
  float acc = 0.f;
#pragma unroll
  for (int b = 0; b < BB; b++)
    acc += comp[r * BB + b] * basis[((size_t)b * in_dim + i) * HDIM + o];
  Wt[t] = f2bu(acc);
}

// ---------- root transpose: rt[o][i] = bf16(root[i][o]) ----------
__global__ void k_troot(const float* __restrict__ root, unsigned short* __restrict__ rt,
                        int in_dim) {
  int t = blockIdx.x * 256 + threadIdx.x;
  if (t >= in_dim * HDIM) return;
  int i = t % in_dim, o = t / in_dim;
  rt[t] = f2bu(root[(size_t)i * HDIM + o]);
}

// ---------- bf16 MFMA GEMM: C[M,256](f32) (+)= A[M,K](bf16) @ Bt[256,K](bf16)^T ----------
// tile 128x128, 4 waves, each wave 64x64 via 4x4 mfma_f32_16x16x32_bf16
// LDS xor-swizzle: element (row, k8-block) stored at col8 = k8 ^ (row&7)
__global__ __launch_bounds__(256) void k_gemm(const unsigned short* __restrict__ A,
                                              const unsigned short* __restrict__ Bt,
                                              float* __restrict__ C,
                                              const float* __restrict__ bias,
                                              int K, int M, int accmode) {
  __shared__ unsigned short As[128 * 64];
  __shared__ unsigned short Bs[128 * 64];
  const int tid = threadIdx.x;
  const int bn = blockIdx.x * 128;
  const int bm = blockIdx.y * 128;
  const int wv = tid >> 6, l = tid & 63;
  const int wr = wv >> 1, wc = wv & 1;
  const int lm = l & 15, lq = l >> 4;
  f32x4 acc[4][4];
#pragma unroll
  for (int mt = 0; mt < 4; mt++)
#pragma unroll
    for (int nt = 0; nt < 4; nt++) acc[mt][nt] = (f32x4){0.f, 0.f, 0.f, 0.f};

  const int arow = tid >> 3;  // 0..31
  const int ak8 = tid & 7;    // 16B chunk within 64-elem row
  const int nkt = K >> 6;

  for (int kt = 0; kt < nkt; kt++) {
    uint4 av[4], bv[4];
#pragma unroll
    for (int p = 0; p < 4; p++) {
      int r = arow + p * 32;
      int gr = bm + r;
      av[p] = (gr < M) ? *(const uint4*)(A + (size_t)gr * K + kt * 64 + ak8 * 8)
                       : make_uint4(0u, 0u, 0u, 0u);
      bv[p] = *(const uint4*)(Bt + (size_t)(bn + r) * K + kt * 64 + ak8 * 8);
    }
    __syncthreads();
#pragma unroll
    for (int p = 0; p < 4; p++) {
      int r = arow + p * 32;
      int col = ak8 ^ (r & 7);
      *(uint4*)(&As[r * 64 + col * 8]) = av[p];
      *(uint4*)(&Bs[r * 64 + col * 8]) = bv[p];
    }
    __syncthreads();
#pragma unroll
    for (int ks = 0; ks < 2; ks++) {
      short8 af[4], bf[4];
#pragma unroll
      for (int mt = 0; mt < 4; mt++) {
        int r = wr * 64 + mt * 16 + lm;
        int c = (ks * 4 + lq) ^ (r & 7);
        af[mt] = *(const short8*)(&As[r * 64 + c * 8]);
      }
#pragma unroll
      for (int nt = 0; nt < 4; nt++) {
        int r = wc * 64 + nt * 16 + lm;
        int c = (ks * 4 + lq) ^ (r & 7);
        bf[nt] = *(const short8*)(&Bs[r * 64 + c * 8]);
      }
#pragma unroll
      for (int mt = 0; mt < 4; mt++)
#pragma unroll
        for (int nt = 0; nt < 4; nt++)
          acc[mt][nt] = __builtin_amdgcn_mfma_f32_16x16x32_bf16(af[mt], bf[nt],
                                                                acc[mt][nt], 0, 0, 0);
    }
  }
  // epilogue: C/D layout col=lane&15, row=(lane>>4)*4+reg
#pragma unroll
  for (int mt = 0; mt < 4; mt++) {
#pragma unroll
    for (int r = 0; r < 4; r++) {
      int row = bm + wr * 64 + mt * 16 + lq * 4 + r;
      if (row >= M) continue;
      float* cp = C + (size_t)row * HDIM + bn + wc * 64;
#pragma unroll
      for (int nt = 0; nt < 4; nt++) {
        int col = nt * 16 + lm;
        float v = acc[mt][nt][r];
        if (accmode) cp[col] += v;
        else cp[col] = v + bias[bn + wc * 64 + col];
      }
    }
  }
}

// ---------- head-softmax attention: fp32 in, bf16 out ----------
__global__ void k_attn(const float* __restrict__ h, const float* __restrict__ att,
                       unsigned short* __restrict__ hb) {
  int gtid = blockIdx.x * 256 + threadIdx.x;
  int node = gtid >> 6;
  int lane = gtid & 63;
  if (node >= NN) return;
  const float* hp = h + (size_t)node * HDIM;
  float v[4], s[4];
#pragma unroll
  for (int hd = 0; hd < 4; hd++) {
    v[hd] = hp[hd * 64 + lane];
    s[hd] = v[hd] * att[hd * 64 + lane];
  }
#pragma unroll
  for (int off = 32; off > 0; off >>= 1) {
#pragma unroll
    for (int hd = 0; hd < 4; hd++) s[hd] += __shfl_xor(s[hd], off, 64);
  }
  float mx = fmaxf(fmaxf(s[0], s[1]), fmaxf(s[2], s[3]));
  float ex[4], sum = 0.f;
#pragma unroll
  for (int hd = 0; hd < 4; hd++) { ex[hd] = __expf(s[hd] - mx); sum += ex[hd]; }
  float inv = 1.0f / sum;
  unsigned short* ob = hb + (size_t)node * HDIM;
#pragma unroll
  for (int hd = 0; hd < 4; hd++) ob[hd * 64 + lane] = f2bu(v[hd] * (ex[hd] * inv));
}

// ---------- prediction head: bf16 h, fp32 weights ----------
__global__ void k_pred(const unsigned short* __restrict__ h, const float* __restrict__ w,
                       const float* __restrict__ b, float* __restrict__ out) {
  int t = blockIdx.x * 256 + threadIdx.x;
  if (t >= NN * 12) return;
  int n = t / 12, j = t - n * 12;
  float acc = b[j];
  const unsigned short* hp = h + (size_t)n * HDIM;
#pragma unroll 4
  for (int k = 0; k < HDIM; k++) acc += bu2f(hp[k]) * w[k * 12 + j];
  out[t] = acc;
}

extern "C" void kernel_launch(void* const* d_in, const int* in_sizes, int n_in,
                              void* d_out, int out_size, void* d_ws, size_t ws_size,
                              hipStream_t stream) {
  const float* x         = (const float*)d_in[0];
  const int*   edge_idx  = (const int*)d_in[1];
  const int*   edge_type = (const int*)d_in[2];
  const int*   gene_idx  = (const int*)d_in[3];
  const int*   path_idx  = (const int*)d_in[4];
  const float* gene_emb  = (const float*)d_in[5];
  const float* path_emb  = (const float*)d_in[6];
  const float* comp1     = (const float*)d_in[7];
  const float* basis1    = (const float*)d_in[8];
  const float* root1     = (const float*)d_in[9];
  const float* bias1     = (const float*)d_in[10];
  const float* att1      = (const float*)d_in[11];
  const float* comp2     = (const float*)d_in[12];
  const float* basis2    = (const float*)d_in[13];
  const float* root2     = (const float*)d_in[14];
  const float* bias2     = (const float*)d_in[15];
  const float* att2      = (const float*)d_in[16];
  const float* pred_w    = (const float*)d_in[17];
  const float* pred_b    = (const float*)d_in[18];
  float* out = (float*)d_out;

  // workspace layout (bytes); peak ~237.4 MB (252 MB proven in round 2)
  char* ws = (char*)d_ws;
  float*          hF   = (float*)(ws);                        // 51,200,000 (shared conv1/conv2 fp32 accum)
  unsigned short* x0b  = (unsigned short*)(ws + 51200000);    // 19,200,000
  unsigned short* h1b  = (unsigned short*)(ws + 70400000);    // 25,600,000
  unsigned short* h2b  = (unsigned short*)(ws + 96000000);    // 25,600,000
  unsigned short* aggB = (unsigned short*)(ws + 121600000);   // 102,400,000 (RC=4, in=256)
  unsigned short* W1t  = (unsigned short*)(ws + 224000000);   // 1,179,648
  unsigned short* W2t  = (unsigned short*)(ws + 225179648);   // 1,572,864
  unsigned short* r1t  = (unsigned short*)(ws + 226752512);   // 98,304
  unsigned short* r2t  = (unsigned short*)(ws + 226850816);   // 131,072
  int*            cnt  = (int*)(ws + 226981888);              // 2,400,000
  int*            off  = (int*)(ws + 229381888);              // 2,400,000
  int*            fill = (int*)(ws + 231781888);              // 2,400,000
  int*            perm = (int*)(ws + 234181888);              // 3,200,000
  int*            bsum = (int*)(ws + 237381888);              // 4 KB
  int*            bscan= (int*)(ws + 237385984);              // 4 KB

  dim3 blk(256);

  // ---- stage 0: features + CSR build + weight prep ----
  k_build_x0<<<dim3((NN * IN1) / 256), blk, 0, stream>>>(x, x0b);
  k_add_emb<<<dim3((NGENE * EMBD) / 256), blk, 0, stream>>>(gene_idx, gene_emb, x0b, NGENE);
  k_add_emb<<<dim3((NPATH * EMBD) / 256), blk, 0, stream>>>(path_idx, path_emb, x0b, NPATH);
  hipMemsetAsync(cnt, 0, NRK * 4, stream);
  hipMemsetAsync(fill, 0, NRK * 4, stream);
  k_count<<<dim3(NE / 256), blk, 0, stream>>>(edge_idx, edge_type, cnt);
  k_scan1<<<dim3(NSB), blk, 0, stream>>>(cnt, bsum);
  k_scan2<<<dim3(1), dim3(1024), 0, stream>>>(bsum, bscan);
  k_scan3<<<dim3(NSB), blk, 0, stream>>>(cnt, bscan, off);
  k_fill<<<dim3(NE / 256), blk, 0, stream>>>(edge_idx, edge_type, off, fill, perm);
  k_wcat<<<dim3((RR * HDIM * IN1) / 256), blk, 0, stream>>>(comp1, basis1, W1t, IN1);
  k_wcat<<<dim3((RR * HDIM * HDIM) / 256), blk, 0, stream>>>(comp2, basis2, W2t, HDIM);
  k_troot<<<dim3((IN1 * HDIM) / 256), blk, 0, stream>>>(root1, r1t, IN1);
  k_troot<<<dim3((HDIM * HDIM) / 256), blk, 0, stream>>>(root2, r2t, HDIM);

  dim3 ggrid(2, 391);        // (n-block, m-block): N-blocks of one M-tile adjacent for L2
  dim3 agrid(NN);            // NN*RC waves / 4 per block

  // ---- conv1 ----
  k_gemm<<<ggrid, blk, 0, stream>>>(x0b, r1t, hF, bias1, IN1, NN, 0);
  for (int c = 0; c < 3; c++) {
    k_agg<<<agrid, blk, 0, stream>>>(edge_idx, perm, off, cnt, x0b, aggB, IN1, c * RC);
    k_gemm<<<ggrid, blk, 0, stream>>>(aggB, W1t + (size_t)c * HDIM * RC * IN1, hF, bias1,
                                      RC * IN1, NN, 1);
  }
  k_attn<<<dim3((NN * 64 + 255) / 256), blk, 0, stream>>>(hF, att1, h1b);

  // ---- conv2 ----
  k_gemm<<<ggrid, blk, 0, stream>>>(h1b, r2t, hF, bias2, HDIM, NN, 0);
  for (int c = 0; c < 3; c++) {
    k_agg<<<agrid, blk, 0, stream>>>(edge_idx, perm, off, cnt, h1b, aggB, HDIM, c * RC);
    k_gemm<<<ggrid, blk, 0, stream>>>(aggB, W2t + (size_t)c * HDIM * RC * HDIM, hF, bias2,
                                      RC * HDIM, NN, 1);
  }
  k_attn<<<dim3((NN * 64 + 255) / 256), blk, 0, stream>>>(hF, att2, h2b);

  // ---- prediction head ----
  k_pred<<<dim3((NN * 12 + 255) / 256), blk, 0, stream>>>(h2b, pred_w, pred_b, out);
}